// Round 1
// baseline (267.849 us; speedup 1.0000x reference)
//
#include <hip/hip_runtime.h>
#include <hip/hip_bf16.h>

// Problem constants: B=4, L=4096, C=1024, H=16, D=64
// qkv GEMM: M=16384, N=3072, K=1024 (NT: both A and W row-major along K)
// out GEMM: M=16384, N=1024, K=1024
//
// Reference quirk: out = swapaxes((b,l,h,d),1,2).reshape(b,l,c) is a SCRAMBLED
// flatten: Y[b,h,l=16q+j,d] -> row (256h+q), col (64j+d) per batch. The
// attention kernel writes directly into that layout so GEMM2 is a plain GEMM.

typedef __attribute__((ext_vector_type(8))) short bf16x8;
typedef __attribute__((ext_vector_type(4))) float f32x4;

__device__ __forceinline__ float bf2f(unsigned short u) {
    union { unsigned int i; float f; } x;
    x.i = ((unsigned int)u) << 16;
    return x.f;
}
__device__ __forceinline__ unsigned short f2bf(float f) {
    unsigned int u = __float_as_uint(f);
    u = (u + 0x7FFFu + ((u >> 16) & 1u)) >> 16;   // RNE
    return (unsigned short)u;
}

// ---------------- cast fp32 -> bf16, vectorized ----------------
__global__ __launch_bounds__(256) void cast_f32_bf16(const float* __restrict__ in,
                                                     unsigned short* __restrict__ out,
                                                     int n4) {
    int i = blockIdx.x * blockDim.x + threadIdx.x;
    int stride = gridDim.x * blockDim.x;
    for (; i < n4; i += stride) {
        float4 v = ((const float4*)in)[i];
        ushort4 o;
        o.x = f2bf(v.x); o.y = f2bf(v.y); o.z = f2bf(v.z); o.w = f2bf(v.w);
        ((ushort4*)out)[i] = o;
    }
}

// ---------------- NT GEMM: C[m,n] = sum_k A[m,k]*B[n,k] + bias[n] -----------
// m97 structure: 128x128 tile, BK=32, 4 waves (2x2), each wave 64x64 via 4x4
// 16x16x32 bf16 MFMA fragments; global_load_lds width=16 staging.
template<int OUTF32>
__global__ __launch_bounds__(256) void gemm_bt(const unsigned short* __restrict__ A,
                                               const unsigned short* __restrict__ B,
                                               const float* __restrict__ bias,
                                               unsigned short* __restrict__ Cb,
                                               float* __restrict__ Cf,
                                               int M, int N, int K) {
    __shared__ __align__(16) unsigned short As[128 * 32];
    __shared__ __align__(16) unsigned short Bs[128 * 32];

    const int tid  = threadIdx.x;
    const int lane = tid & 63;
    const int wave = tid >> 6;
    const int wr = wave >> 1, wc = wave & 1;
    const int tileN = blockIdx.x * 128;
    const int tileM = blockIdx.y * 128;
    const int fr = lane & 15;        // 16-dim index within fragment
    const int fq = lane >> 4;        // k-chunk / row-quad selector

    // staging chunks: 512 x 16B per tile; thread t covers chunks t and t+256
    const int c0 = tid,        r0 = c0 >> 2, kc0 = (c0 & 3) << 3;
    const int c1 = tid + 256,  r1 = c1 >> 2, kc1 = (c1 & 3) << 3;

    const unsigned short* Abase = A + (size_t)tileM * K;
    const unsigned short* Bbase = B + (size_t)tileN * K;

    f32x4 acc[4][4];
#pragma unroll
    for (int m = 0; m < 4; ++m)
#pragma unroll
        for (int n = 0; n < 4; ++n) acc[m][n] = (f32x4){0.f, 0.f, 0.f, 0.f};

    for (int k0 = 0; k0 < K; k0 += 32) {
        __syncthreads();   // previous iteration's readers done
        __builtin_amdgcn_global_load_lds(
            (const __attribute__((address_space(1))) void*)(Abase + (size_t)r0 * K + k0 + kc0),
            (__attribute__((address_space(3))) void*)(As + c0 * 8), 16, 0, 0);
        __builtin_amdgcn_global_load_lds(
            (const __attribute__((address_space(1))) void*)(Abase + (size_t)r1 * K + k0 + kc1),
            (__attribute__((address_space(3))) void*)(As + c1 * 8), 16, 0, 0);
        __builtin_amdgcn_global_load_lds(
            (const __attribute__((address_space(1))) void*)(Bbase + (size_t)r0 * K + k0 + kc0),
            (__attribute__((address_space(3))) void*)(Bs + c0 * 8), 16, 0, 0);
        __builtin_amdgcn_global_load_lds(
            (const __attribute__((address_space(1))) void*)(Bbase + (size_t)r1 * K + k0 + kc1),
            (__attribute__((address_space(3))) void*)(Bs + c1 * 8), 16, 0, 0);
        __syncthreads();   // drains vmcnt -> staged data visible

        bf16x8 af[4], bf[4];
#pragma unroll
        for (int m = 0; m < 4; ++m)
            af[m] = *(const bf16x8*)&As[(wr * 64 + m * 16 + fr) * 32 + fq * 8];
#pragma unroll
        for (int n = 0; n < 4; ++n)
            bf[n] = *(const bf16x8*)&Bs[(wc * 64 + n * 16 + fr) * 32 + fq * 8];
#pragma unroll
        for (int m = 0; m < 4; ++m)
#pragma unroll
            for (int n = 0; n < 4; ++n)
                acc[m][n] = __builtin_amdgcn_mfma_f32_16x16x32_bf16(af[m], bf[n], acc[m][n], 0, 0, 0);
    }

    // epilogue: C/D layout col=lane&15, row=(lane>>4)*4+reg
#pragma unroll
    for (int n = 0; n < 4; ++n) {
        const int col = tileN + wc * 64 + n * 16 + fr;
        const float bv = bias[col];
#pragma unroll
        for (int m = 0; m < 4; ++m) {
#pragma unroll
            for (int r = 0; r < 4; ++r) {
                const int row = tileM + wr * 64 + m * 16 + fq * 4 + r;
                const float v = acc[m][n][r] + bv;
                if (OUTF32) Cf[(size_t)row * N + col] = v;
                else        Cb[(size_t)row * N + col] = f2bf(v);
            }
        }
    }
}

// ---------------- per-token head-attention ----------------
// One token per wave, 4 waves/block. qkv row layout: [3][16][64] bf16.
// Writes the SCRAMBLED layout: scr[(b*4096 + 256*h + (l>>4))*1024 + (l&15)*64 + d]
__global__ __launch_bounds__(256) void attn_kernel(const unsigned short* __restrict__ qkv,
                                                   unsigned short* __restrict__ scr) {
    __shared__ __align__(16) unsigned short sbuf[4][3072];
    __shared__ float Pl[4][256];

    const int wave = threadIdx.x >> 6, lane = threadIdx.x & 63;
    const int token = blockIdx.x * 4 + wave;
    const int b = token >> 12, l = token & 4095;

    const unsigned short* src = qkv + (size_t)token * 3072;
#pragma unroll
    for (int i = 0; i < 6; ++i) {
        int off = (i * 64 + lane) * 8;
        *(bf16x8*)&sbuf[wave][off] = *(const bf16x8*)&src[off];
    }
    __syncthreads();

    const unsigned short* sq = sbuf[wave];

    // scores: lane handles (h,g) pairs p = r*64+lane; p == h*16+g directly
    float sv[4];
#pragma unroll
    for (int r = 0; r < 4; ++r) {
        const int p = r * 64 + lane;
        const int h = p >> 4, g = p & 15;
        float acc = 0.f;
#pragma unroll
        for (int d8 = 0; d8 < 8; ++d8) {
            bf16x8 qa = *(const bf16x8*)&sq[h * 64 + d8 * 8];
            bf16x8 kb = *(const bf16x8*)&sq[1024 + g * 64 + d8 * 8];
#pragma unroll
            for (int j = 0; j < 8; ++j)
                acc += bf2f((unsigned short)qa[j]) * bf2f((unsigned short)kb[j]);
        }
        sv[r] = acc * 0.125f;   // scale = d^-0.5 = 64^-0.5
    }

    // softmax over g: rows of 16 live in contiguous 16-lane groups
#pragma unroll
    for (int r = 0; r < 4; ++r) {
        float m = sv[r];
        m = fmaxf(m, __shfl_xor(m, 1));
        m = fmaxf(m, __shfl_xor(m, 2));
        m = fmaxf(m, __shfl_xor(m, 4));
        m = fmaxf(m, __shfl_xor(m, 8));
        float e = __expf(sv[r] - m);
        float s = e;
        s += __shfl_xor(s, 1);
        s += __shfl_xor(s, 2);
        s += __shfl_xor(s, 4);
        s += __shfl_xor(s, 8);
        Pl[wave][r * 64 + lane] = e / s;
    }
    __syncthreads();

    // PV: head h per rep, lane = d. v[g][lane] hoisted to registers.
    float vreg[16];
#pragma unroll
    for (int g = 0; g < 16; ++g) vreg[g] = bf2f(sq[2048 + g * 64 + lane]);

    const int q_ = l >> 4, j = l & 15;
    const size_t base = ((size_t)b * 4096 + q_) * 1024 + j * 64 + lane;
#pragma unroll
    for (int h = 0; h < 16; ++h) {
        float acc = 0.f;
#pragma unroll
        for (int g = 0; g < 16; ++g) acc += Pl[wave][h * 16 + g] * vreg[g];
        scr[base + (size_t)h * 256 * 1024] = f2bf(acc);
    }
}

// ---------------- launch ----------------
extern "C" void kernel_launch(void* const* d_in, const int* in_sizes, int n_in,
                              void* d_out, int out_size, void* d_ws, size_t ws_size,
                              hipStream_t stream) {
    const float* x    = (const float*)d_in[0];   // [4,4096,1024]
    const float* Wqkv = (const float*)d_in[1];   // [3072,1024]
    const float* bqkv = (const float*)d_in[2];   // [3072]
    const float* Wout = (const float*)d_in[3];   // [1024,1024]
    const float* bout = (const float*)d_in[4];   // [1024]
    float* out = (float*)d_out;                  // [4,4096,1024] fp32

    char* ws = (char*)d_ws;
    unsigned short* xb   = (unsigned short*)(ws);                 // 33,554,432 B
    unsigned short* wqb  = (unsigned short*)(ws + 33554432);      //  6,291,456 B
    unsigned short* wob  = (unsigned short*)(ws + 39845888);      //  2,097,152 B
    unsigned short* qkvb = (unsigned short*)(ws + 41943040);      // 100,663,296 B
    unsigned short* scr  = (unsigned short*)(ws + 142606336);     // 33,554,432 B  (total 176,160,768)

    cast_f32_bf16<<<2048, 256, 0, stream>>>(x,    xb,  4194304);
    cast_f32_bf16<<<512,  256, 0, stream>>>(Wqkv, wqb, 786432);
    cast_f32_bf16<<<256,  256, 0, stream>>>(Wout, wob, 262144);

    // qkv = x @ Wqkv^T + bqkv   (M=16384, N=3072, K=1024), bf16 out
    gemm_bt<0><<<dim3(24, 128), 256, 0, stream>>>(xb, wqb, bqkv, qkvb, nullptr, 16384, 3072, 1024);

    // per-token head attention -> scrambled layout
    attn_kernel<<<4096, 256, 0, stream>>>(qkvb, scr);

    // out = scr @ Wout^T + bout  (M=16384, N=1024, K=1024), fp32 out
    gemm_bt<1><<<dim3(8, 128), 256, 0, stream>>>(scr, wob, bout, nullptr, out, 16384, 1024, 1024);
}

// Round 2
// 211.872 us; speedup vs baseline: 1.2642x; 1.2642x over previous
//
#include <hip/hip_runtime.h>
#include <hip/hip_bf16.h>

// B=4, L=4096, C=1024, H=16, D=64
// GEMM1: qkv = x@Wqkv^T+b  (M=16384,N=3072,K=1024)  -> bf16
// attn: per-token 16x16 head-attention, writes scrambled layout
// GEMM2: out = scr@Wout^T+b (M=16384,N=1024,K=1024) -> fp32
//
// gemm256: 256x256 tile, BK=64, 8 waves(2x4), 128KiB LDS dbuf, 4 quadrant
// phases/K-tile with counted vmcnt(4) (T3+T4), XOR bank swizzle (T2, rule#21
// both-sides: pre-swizzled global source + swizzled ds_read, linear gload_lds
// dest), setprio around MFMA (T5), bijective XCD swizzle (T1).

typedef __attribute__((ext_vector_type(8))) short bf16x8;
typedef __attribute__((ext_vector_type(4))) float f32x4;

__device__ __forceinline__ float bf2f(unsigned short u) {
    union { unsigned int i; float f; } x;
    x.i = ((unsigned int)u) << 16;
    return x.f;
}
__device__ __forceinline__ unsigned short f2bf(float f) {
    unsigned int u = __float_as_uint(f);
    u = (u + 0x7FFFu + ((u >> 16) & 1u)) >> 16;   // RNE
    return (unsigned short)u;
}

#define VMCNT4() asm volatile("s_waitcnt vmcnt(4)" ::: "memory")
#define VMCNT0() asm volatile("s_waitcnt vmcnt(0)" ::: "memory")
#define LGKM0()  asm volatile("s_waitcnt lgkmcnt(0)" ::: "memory")
#define BAR()    __builtin_amdgcn_s_barrier()

// ---------------- cast fp32 -> bf16, vectorized ----------------
__global__ __launch_bounds__(256) void cast_f32_bf16(const float* __restrict__ in,
                                                     unsigned short* __restrict__ out,
                                                     int n4) {
    int i = blockIdx.x * blockDim.x + threadIdx.x;
    int stride = gridDim.x * blockDim.x;
    for (; i < n4; i += stride) {
        float4 v = ((const float4*)in)[i];
        ushort4 o;
        o.x = f2bf(v.x); o.y = f2bf(v.y); o.z = f2bf(v.z); o.w = f2bf(v.w);
        ((ushort4*)out)[i] = o;
    }
}

// ---------------- 256^2 deep-pipelined NT GEMM ----------------
// C[m,n] = sum_k A[m,k]*B[n,k] + bias[n]
// LDS half-tile = [128 rows][64 cols] bf16 = 16KB; chunk = 16B (8 bf16).
// Swizzle: LDS slot s at row r holds global chunk j = s ^ (r&7).
template<int OUTF32>
__global__ __launch_bounds__(512, 2) void gemm256(const unsigned short* __restrict__ A,
                                                  const unsigned short* __restrict__ B,
                                                  const float* __restrict__ bias,
                                                  unsigned short* __restrict__ Cb,
                                                  float* __restrict__ Cf,
                                                  int M, int N, int K, int NXT) {
    __shared__ __align__(16) unsigned short lds[2][2][2][8192]; // [buf][A/B][half][128*64]

    const int tid  = threadIdx.x;
    const int lane = tid & 63;
    const int wave = tid >> 6;
    const int wr = wave >> 2;        // 0..1  (M side)
    const int wc = wave & 3;         // 0..3  (N side)
    const int fr = lane & 15;
    const int fq = lane >> 4;
    const int frx = fr & 7;

    // T1: bijective XCD swizzle (grid size % 8 == 0 at all call sites)
    const int nwg  = gridDim.x;
    const int orig = blockIdx.x;
    const int wg   = (orig & 7) * (nwg >> 3) + (orig >> 3);
    const int tileM = (wg / NXT) * 256;
    const int tileN = (wg % NXT) * 256;

    // staging: thread covers chunks tid and tid+512 of a half-tile
    const int r8  = tid >> 3;                 // row 0..63 (first load), +64 second
    const int jsw = (tid & 7) ^ (r8 & 7);     // pre-swizzled global chunk index
    const unsigned short* Ap = A;
    const unsigned short* Bp = B;

#define STAGE(nb, OPp, HH, ktt) do {                                                   \
    const unsigned short* gb = (OPp) ? Bp : Ap;                                        \
    const int rb = ((OPp) ? tileN : tileM) + (HH) * 128 + r8;                          \
    const unsigned short* s0 = gb + (size_t)rb * K + (ktt) * 64 + jsw * 8;             \
    unsigned short* d0 = &lds[nb][OPp][HH][tid * 8];                                   \
    __builtin_amdgcn_global_load_lds((const __attribute__((address_space(1))) void*)s0,\
        (__attribute__((address_space(3))) void*)d0, 16, 0, 0);                        \
    __builtin_amdgcn_global_load_lds(                                                  \
        (const __attribute__((address_space(1))) void*)(s0 + (size_t)64 * K),          \
        (__attribute__((address_space(3))) void*)(d0 + 4096), 16, 0, 0);               \
} while (0)

// quadrant (h,g): m-reps h*4..h*4+3, n-reps g*2..g*2+1, both k-steps
#define QUAD_READ(h, g) do {                                                           \
    _Pragma("unroll") for (int i2 = 0; i2 < 4; ++i2) {                                 \
        const int ar = (wr * 64 + i2 * 16 + fr) * 64;                                  \
        af[i2][0] = *(const bf16x8*)&lds[cur][0][h][ar + ((fq ^ frx) << 3)];           \
        af[i2][1] = *(const bf16x8*)&lds[cur][0][h][ar + (((4 + fq) ^ frx) << 3)];     \
    }                                                                                  \
    _Pragma("unroll") for (int j2 = 0; j2 < 2; ++j2) {                                 \
        const int br = (wc * 32 + j2 * 16 + fr) * 64;                                  \
        bfr[j2][0] = *(const bf16x8*)&lds[cur][1][g][br + ((fq ^ frx) << 3)];          \
        bfr[j2][1] = *(const bf16x8*)&lds[cur][1][g][br + (((4 + fq) ^ frx) << 3)];    \
    }                                                                                  \
} while (0)

#define QUAD_MFMA(h, g) do {                                                           \
    __builtin_amdgcn_s_setprio(1);                                                     \
    _Pragma("unroll") for (int i2 = 0; i2 < 4; ++i2)                                   \
    _Pragma("unroll") for (int j2 = 0; j2 < 2; ++j2) {                                 \
        acc[(h)*4+i2][(g)*2+j2] = __builtin_amdgcn_mfma_f32_16x16x32_bf16(             \
            af[i2][0], bfr[j2][0], acc[(h)*4+i2][(g)*2+j2], 0, 0, 0);                  \
        acc[(h)*4+i2][(g)*2+j2] = __builtin_amdgcn_mfma_f32_16x16x32_bf16(             \
            af[i2][1], bfr[j2][1], acc[(h)*4+i2][(g)*2+j2], 0, 0, 0);                  \
    }                                                                                  \
    __builtin_amdgcn_s_setprio(0);                                                     \
} while (0)

    f32x4 acc[8][4];
#pragma unroll
    for (int i = 0; i < 8; ++i)
#pragma unroll
        for (int j = 0; j < 4; ++j) acc[i][j] = (f32x4){0.f, 0.f, 0.f, 0.f};

    // prologue: stage tile 0 in drain order A0,B0,B1,A1; leave {B1,A1} in flight
    STAGE(0, 0, 0, 0);
    STAGE(0, 1, 0, 0);
    STAGE(0, 1, 1, 0);
    STAGE(0, 0, 1, 0);
    VMCNT4();
    BAR();

    const int NT = K >> 6;
    int cur = 0;
    for (int kt = 0; kt < NT - 1; ++kt) {
        const int nb = cur ^ 1;
        bf16x8 af[4][2], bfr[2][2];
        // P0: quad(A0,B0); stage next A0; wait -> current B1 lands
        QUAD_READ(0, 0); STAGE(nb, 0, 0, kt + 1); VMCNT4(); BAR(); LGKM0(); QUAD_MFMA(0, 0);
        // P1: quad(A0,B1); stage next B0; wait -> current A1 lands
        QUAD_READ(0, 1); STAGE(nb, 1, 0, kt + 1); VMCNT4(); BAR(); LGKM0(); QUAD_MFMA(0, 1);
        // P2: quad(A1,B0); stage next B1; no wait needed
        QUAD_READ(1, 0); STAGE(nb, 1, 1, kt + 1); BAR(); LGKM0(); QUAD_MFMA(1, 0);
        // P3: quad(A1,B1); stage next A1; wait -> next A0,B0 land
        QUAD_READ(1, 1); STAGE(nb, 0, 1, kt + 1); VMCNT4(); BAR(); LGKM0(); QUAD_MFMA(1, 1);
        cur = nb;
    }
    // final K-tile: drain everything, no stages
    VMCNT0();
    BAR();
    {
        bf16x8 af[4][2], bfr[2][2];
        QUAD_READ(0, 0); LGKM0(); QUAD_MFMA(0, 0);
        QUAD_READ(0, 1); LGKM0(); QUAD_MFMA(0, 1);
        QUAD_READ(1, 0); LGKM0(); QUAD_MFMA(1, 0);
        QUAD_READ(1, 1); LGKM0(); QUAD_MFMA(1, 1);
    }

    // epilogue: C/D layout col=lane&15, row=(lane>>4)*4+reg
#pragma unroll
    for (int i = 0; i < 8; ++i) {
        const int row = tileM + (i >> 2) * 128 + wr * 64 + (i & 3) * 16 + fq * 4;
#pragma unroll
        for (int j = 0; j < 4; ++j) {
            const int col = tileN + (j >> 1) * 128 + wc * 32 + (j & 1) * 16 + fr;
            const float bv = bias[col];
#pragma unroll
            for (int r = 0; r < 4; ++r) {
                const float v = acc[i][j][r] + bv;
                if (OUTF32) Cf[(size_t)(row + r) * N + col] = v;
                else        Cb[(size_t)(row + r) * N + col] = f2bf(v);
            }
        }
    }
#undef STAGE
#undef QUAD_READ
#undef QUAD_MFMA
}

// ---------------- per-token head-attention ----------------
// One token per wave, 4 waves/block. qkv row layout: [3][16][64] bf16.
// Writes the SCRAMBLED layout: scr[(b*4096 + 256*h + (l>>4))*1024 + (l&15)*64 + d]
__global__ __launch_bounds__(256) void attn_kernel(const unsigned short* __restrict__ qkv,
                                                   unsigned short* __restrict__ scr) {
    __shared__ __align__(16) unsigned short sbuf[4][3072];
    __shared__ float Pl[4][256];

    const int wave = threadIdx.x >> 6, lane = threadIdx.x & 63;
    const int token = blockIdx.x * 4 + wave;
    const int b = token >> 12, l = token & 4095;

    const unsigned short* src = qkv + (size_t)token * 3072;
#pragma unroll
    for (int i = 0; i < 6; ++i) {
        int off = (i * 64 + lane) * 8;
        *(bf16x8*)&sbuf[wave][off] = *(const bf16x8*)&src[off];
    }
    __syncthreads();

    const unsigned short* sq = sbuf[wave];

    float sv[4];
#pragma unroll
    for (int r = 0; r < 4; ++r) {
        const int p = r * 64 + lane;
        const int h = p >> 4, g = p & 15;
        float acc = 0.f;
#pragma unroll
        for (int d8 = 0; d8 < 8; ++d8) {
            bf16x8 qa = *(const bf16x8*)&sq[h * 64 + d8 * 8];
            bf16x8 kb = *(const bf16x8*)&sq[1024 + g * 64 + d8 * 8];
#pragma unroll
            for (int j = 0; j < 8; ++j)
                acc += bf2f((unsigned short)qa[j]) * bf2f((unsigned short)kb[j]);
        }
        sv[r] = acc * 0.125f;
    }

#pragma unroll
    for (int r = 0; r < 4; ++r) {
        float m = sv[r];
        m = fmaxf(m, __shfl_xor(m, 1));
        m = fmaxf(m, __shfl_xor(m, 2));
        m = fmaxf(m, __shfl_xor(m, 4));
        m = fmaxf(m, __shfl_xor(m, 8));
        float e = __expf(sv[r] - m);
        float s = e;
        s += __shfl_xor(s, 1);
        s += __shfl_xor(s, 2);
        s += __shfl_xor(s, 4);
        s += __shfl_xor(s, 8);
        Pl[wave][r * 64 + lane] = e / s;
    }
    __syncthreads();

    float vreg[16];
#pragma unroll
    for (int g = 0; g < 16; ++g) vreg[g] = bf2f(sq[2048 + g * 64 + lane]);

    const int q_ = l >> 4, j = l & 15;
    const size_t base = ((size_t)b * 4096 + q_) * 1024 + j * 64 + lane;
#pragma unroll
    for (int h = 0; h < 16; ++h) {
        float acc = 0.f;
#pragma unroll
        for (int g = 0; g < 16; ++g) acc += Pl[wave][h * 16 + g] * vreg[g];
        scr[base + (size_t)h * 256 * 1024] = f2bf(acc);
    }
}

// ---------------- launch ----------------
extern "C" void kernel_launch(void* const* d_in, const int* in_sizes, int n_in,
                              void* d_out, int out_size, void* d_ws, size_t ws_size,
                              hipStream_t stream) {
    const float* x    = (const float*)d_in[0];   // [4,4096,1024]
    const float* Wqkv = (const float*)d_in[1];   // [3072,1024]
    const float* bqkv = (const float*)d_in[2];   // [3072]
    const float* Wout = (const float*)d_in[3];   // [1024,1024]
    const float* bout = (const float*)d_in[4];   // [1024]
    float* out = (float*)d_out;                  // [4,4096,1024] fp32

    char* ws = (char*)d_ws;
    unsigned short* xb   = (unsigned short*)(ws);
    unsigned short* wqb  = (unsigned short*)(ws + 33554432);
    unsigned short* wob  = (unsigned short*)(ws + 39845888);
    unsigned short* qkvb = (unsigned short*)(ws + 41943040);
    unsigned short* scr  = (unsigned short*)(ws + 142606336);

    cast_f32_bf16<<<2048, 256, 0, stream>>>(x,    xb,  4194304);
    cast_f32_bf16<<<512,  256, 0, stream>>>(Wqkv, wqb, 786432);
    cast_f32_bf16<<<256,  256, 0, stream>>>(Wout, wob, 262144);

    // qkv = x @ Wqkv^T + bqkv  (M=16384, N=3072, K=1024), bf16 out; 768 blocks
    gemm256<0><<<768, 512, 0, stream>>>(xb, wqb, bqkv, qkvb, nullptr, 16384, 3072, 1024, 12);

    // per-token head attention -> scrambled layout
    attn_kernel<<<4096, 256, 0, stream>>>(qkvb, scr);

    // out = scr @ Wout^T + bout  (M=16384, N=1024, K=1024), fp32 out; 256 blocks
    gemm256<1><<<256, 512, 0, stream>>>(scr, wob, bout, nullptr, out, 16384, 1024, 1024, 4);
}

// Round 3
// 197.788 us; speedup vs baseline: 1.3542x; 1.0712x over previous
//
#include <hip/hip_runtime.h>
#include <hip/hip_bf16.h>

// B=4, L=4096, C=1024, H=16, D=64
// GEMM1: qkv = x@Wqkv^T+b  (M=16384,N=3072,K=1024)  -> bf16
// attn: per-token 16x16 head-attention, writes scrambled layout
// GEMM2: out = scr@Wout^T+b (M=16384,N=1024,K=1024) -> fp32
//
// gemm256: 256x256 tile, BK=64, 8 waves(2x4), 128KiB LDS dbuf, 4 phases/K-tile
// with counted vmcnt(4) (T3+T4), XOR bank swizzle (T2, both-sides rule#21),
// setprio (T5), bijective XCD swizzle (T1). Round-3 change: minimal LDS reads
// (24 b128/wave/K-tile, was 48) — B-frags held across the K-tile, A-frags
// reused across both B-halves. Phase reads: 12/4/8/0.

typedef __attribute__((ext_vector_type(8))) short bf16x8;
typedef __attribute__((ext_vector_type(4))) float f32x4;

__device__ __forceinline__ float bf2f(unsigned short u) {
    union { unsigned int i; float f; } x;
    x.i = ((unsigned int)u) << 16;
    return x.f;
}
__device__ __forceinline__ unsigned short f2bf(float f) {
    unsigned int u = __float_as_uint(f);
    u = (u + 0x7FFFu + ((u >> 16) & 1u)) >> 16;   // RNE
    return (unsigned short)u;
}

#define VMCNT4() asm volatile("s_waitcnt vmcnt(4)" ::: "memory")
#define VMCNT0() asm volatile("s_waitcnt vmcnt(0)" ::: "memory")
#define LGKM0()  asm volatile("s_waitcnt lgkmcnt(0)" ::: "memory")
#define BAR()    __builtin_amdgcn_s_barrier()

// ---------------- fused cast fp32 -> bf16 for x, Wqkv, Wout ----------------
// virtual concat in float4 units: x 4194304 | Wqkv 786432 | Wout 262144
__global__ __launch_bounds__(256) void cast_all(const float* __restrict__ x,
                                                const float* __restrict__ wq,
                                                const float* __restrict__ wo,
                                                unsigned short* __restrict__ xb,
                                                unsigned short* __restrict__ wqb,
                                                unsigned short* __restrict__ wob) {
    const size_t base = (size_t)blockIdx.x * 2048 + threadIdx.x;
#pragma unroll
    for (int it = 0; it < 8; ++it) {
        size_t i = base + (size_t)it * 256;
        const float4* s; ushort4* d; size_t off;
        if (i < 4194304)      { s = (const float4*)x;  d = (ushort4*)xb;  off = i; }
        else if (i < 4980736) { s = (const float4*)wq; d = (ushort4*)wqb; off = i - 4194304; }
        else                  { s = (const float4*)wo; d = (ushort4*)wob; off = i - 4980736; }
        float4 v = s[off];
        ushort4 o;
        o.x = f2bf(v.x); o.y = f2bf(v.y); o.z = f2bf(v.z); o.w = f2bf(v.w);
        d[off] = o;
    }
}

// ---------------- 256^2 deep-pipelined NT GEMM ----------------
// C[m,n] = sum_k A[m,k]*B[n,k] + bias[n]
// LDS half-tile = [128 rows][64 cols] bf16 = 16KB; chunk = 16B (8 bf16).
// Swizzle: LDS slot s at row r holds global chunk j = s ^ (r&7).
template<int OUTF32>
__global__ __launch_bounds__(512, 2) void gemm256(const unsigned short* __restrict__ A,
                                                  const unsigned short* __restrict__ B,
                                                  const float* __restrict__ bias,
                                                  unsigned short* __restrict__ Cb,
                                                  float* __restrict__ Cf,
                                                  int M, int N, int K, int NXT) {
    __shared__ __align__(16) unsigned short lds[2][2][2][8192]; // [buf][A/B][half][128*64]

    const int tid  = threadIdx.x;
    const int lane = tid & 63;
    const int wave = tid >> 6;
    const int wr = wave >> 2;        // 0..1  (M side)
    const int wc = wave & 3;         // 0..3  (N side)
    const int fr = lane & 15;
    const int fq = lane >> 4;
    const int frx = fr & 7;

    // T1: bijective XCD swizzle (grid size % 8 == 0 at all call sites)
    const int nwg  = gridDim.x;
    const int orig = blockIdx.x;
    const int wg   = (orig & 7) * (nwg >> 3) + (orig >> 3);
    const int tileM = (wg / NXT) * 256;
    const int tileN = (wg % NXT) * 256;

    // staging: thread covers chunks tid and tid+512 of a half-tile
    const int r8  = tid >> 3;                 // row 0..63 (first load), +64 second
    const int jsw = (tid & 7) ^ (r8 & 7);     // pre-swizzled global chunk index
    const unsigned short* Ap = A;
    const unsigned short* Bp = B;

#define STAGE(nb, OPp, HH, ktt) do {                                                   \
    const unsigned short* gb = (OPp) ? Bp : Ap;                                        \
    const int rb = ((OPp) ? tileN : tileM) + (HH) * 128 + r8;                          \
    const unsigned short* s0 = gb + (size_t)rb * K + (ktt) * 64 + jsw * 8;             \
    unsigned short* d0 = &lds[nb][OPp][HH][tid * 8];                                   \
    __builtin_amdgcn_global_load_lds((const __attribute__((address_space(1))) void*)s0,\
        (__attribute__((address_space(3))) void*)d0, 16, 0, 0);                        \
    __builtin_amdgcn_global_load_lds(                                                  \
        (const __attribute__((address_space(1))) void*)(s0 + (size_t)64 * K),          \
        (__attribute__((address_space(3))) void*)(d0 + 4096), 16, 0, 0);               \
} while (0)

// read A-half h into af (8 x b128)
#define READ_A(h) do {                                                                 \
    _Pragma("unroll") for (int i2 = 0; i2 < 4; ++i2) {                                 \
        const int ar = (wr * 64 + i2 * 16 + fr) * 64;                                  \
        af[i2][0] = *(const bf16x8*)&lds[cur][0][h][ar + ((fq ^ frx) << 3)];           \
        af[i2][1] = *(const bf16x8*)&lds[cur][0][h][ar + (((4 + fq) ^ frx) << 3)];     \
    }                                                                                  \
} while (0)

// read B-half g into bfr[2g..2g+1] (4 x b128)
#define READ_B(g) do {                                                                 \
    _Pragma("unroll") for (int j2 = 0; j2 < 2; ++j2) {                                 \
        const int br = (wc * 32 + j2 * 16 + fr) * 64;                                  \
        bfr[2*(g)+j2][0] = *(const bf16x8*)&lds[cur][1][g][br + ((fq ^ frx) << 3)];    \
        bfr[2*(g)+j2][1] = *(const bf16x8*)&lds[cur][1][g][br + (((4 + fq) ^ frx) << 3)];\
    }                                                                                  \
} while (0)

#define MFMA_Q(h, g) do {                                                              \
    __builtin_amdgcn_s_setprio(1);                                                     \
    _Pragma("unroll") for (int i2 = 0; i2 < 4; ++i2)                                   \
    _Pragma("unroll") for (int j2 = 0; j2 < 2; ++j2) {                                 \
        acc[(h)*4+i2][(g)*2+j2] = __builtin_amdgcn_mfma_f32_16x16x32_bf16(             \
            af[i2][0], bfr[2*(g)+j2][0], acc[(h)*4+i2][(g)*2+j2], 0, 0, 0);            \
        acc[(h)*4+i2][(g)*2+j2] = __builtin_amdgcn_mfma_f32_16x16x32_bf16(             \
            af[i2][1], bfr[2*(g)+j2][1], acc[(h)*4+i2][(g)*2+j2], 0, 0, 0);            \
    }                                                                                  \
    __builtin_amdgcn_s_setprio(0);                                                     \
} while (0)

    f32x4 acc[8][4];
#pragma unroll
    for (int i = 0; i < 8; ++i)
#pragma unroll
        for (int j = 0; j < 4; ++j) acc[i][j] = (f32x4){0.f, 0.f, 0.f, 0.f};

    // prologue: stage tile 0 in order A0,B0,B1,A1; drain A0,B0; leave {B1,A1}
    STAGE(0, 0, 0, 0);
    STAGE(0, 1, 0, 0);
    STAGE(0, 1, 1, 0);
    STAGE(0, 0, 1, 0);
    VMCNT4();
    BAR();

    const int NT = K >> 6;
    int cur = 0;
    for (int kt = 0; kt < NT - 1; ++kt) {
        const int nb = cur ^ 1;
        bf16x8 af[4][2], bfr[4][2];
        // P0: read A0+B0; stage next A0; drain current B1
        READ_A(0); READ_B(0); STAGE(nb, 0, 0, kt + 1); VMCNT4(); BAR(); LGKM0(); MFMA_Q(0, 0);
        // P1: read B1 (af reused); stage next B0; drain current A1
        READ_B(1); STAGE(nb, 1, 0, kt + 1); VMCNT4(); BAR(); LGKM0(); MFMA_Q(0, 1);
        // P2: read A1 (bfr held); stage next B1; no wait
        READ_A(1); STAGE(nb, 1, 1, kt + 1); BAR(); LGKM0(); MFMA_Q(1, 0);
        // P3: no reads; stage next A1; drain next A0,B0
        STAGE(nb, 0, 1, kt + 1); VMCNT4(); BAR(); MFMA_Q(1, 1);
        cur = nb;
    }
    // final K-tile: drain everything once, then compute (no stages)
    VMCNT0();
    BAR();
    {
        bf16x8 af[4][2], bfr[4][2];
        READ_A(0); READ_B(0); LGKM0(); MFMA_Q(0, 0);
        READ_B(1);            LGKM0(); MFMA_Q(0, 1);
        READ_A(1);            LGKM0(); MFMA_Q(1, 0);
                                       MFMA_Q(1, 1);
    }

    // epilogue: C/D layout col=lane&15, row=(lane>>4)*4+reg
#pragma unroll
    for (int i = 0; i < 8; ++i) {
        const int row = tileM + (i >> 2) * 128 + wr * 64 + (i & 3) * 16 + fq * 4;
#pragma unroll
        for (int j = 0; j < 4; ++j) {
            const int col = tileN + (j >> 1) * 128 + wc * 32 + (j & 1) * 16 + fr;
            const float bv = bias[col];
#pragma unroll
            for (int r = 0; r < 4; ++r) {
                const float v = acc[i][j][r] + bv;
                if (OUTF32) Cf[(size_t)(row + r) * N + col] = v;
                else        Cb[(size_t)(row + r) * N + col] = f2bf(v);
            }
        }
    }
#undef STAGE
#undef READ_A
#undef READ_B
#undef MFMA_Q
}

// ---------------- per-token head-attention ----------------
// One token per wave, 4 waves/block. qkv row layout: [3][16][64] bf16.
// Writes the SCRAMBLED layout: scr[(b*4096 + 256*h + (l>>4))*1024 + (l&15)*64 + d]
__global__ __launch_bounds__(256) void attn_kernel(const unsigned short* __restrict__ qkv,
                                                   unsigned short* __restrict__ scr) {
    __shared__ __align__(16) unsigned short sbuf[4][3072];
    __shared__ float Pl[4][256];

    const int wave = threadIdx.x >> 6, lane = threadIdx.x & 63;
    const int token = blockIdx.x * 4 + wave;
    const int b = token >> 12, l = token & 4095;

    const unsigned short* src = qkv + (size_t)token * 3072;
#pragma unroll
    for (int i = 0; i < 6; ++i) {
        int off = (i * 64 + lane) * 8;
        *(bf16x8*)&sbuf[wave][off] = *(const bf16x8*)&src[off];
    }
    __syncthreads();

    const unsigned short* sq = sbuf[wave];

    float sv[4];
#pragma unroll
    for (int r = 0; r < 4; ++r) {
        const int p = r * 64 + lane;
        const int h = p >> 4, g = p & 15;
        float acc = 0.f;
#pragma unroll
        for (int d8 = 0; d8 < 8; ++d8) {
            bf16x8 qa = *(const bf16x8*)&sq[h * 64 + d8 * 8];
            bf16x8 kb = *(const bf16x8*)&sq[1024 + g * 64 + d8 * 8];
#pragma unroll
            for (int j = 0; j < 8; ++j)
                acc += bf2f((unsigned short)qa[j]) * bf2f((unsigned short)kb[j]);
        }
        sv[r] = acc * 0.125f;
    }

#pragma unroll
    for (int r = 0; r < 4; ++r) {
        float m = sv[r];
        m = fmaxf(m, __shfl_xor(m, 1));
        m = fmaxf(m, __shfl_xor(m, 2));
        m = fmaxf(m, __shfl_xor(m, 4));
        m = fmaxf(m, __shfl_xor(m, 8));
        float e = __expf(sv[r] - m);
        float s = e;
        s += __shfl_xor(s, 1);
        s += __shfl_xor(s, 2);
        s += __shfl_xor(s, 4);
        s += __shfl_xor(s, 8);
        Pl[wave][r * 64 + lane] = e / s;
    }
    __syncthreads();

    float vreg[16];
#pragma unroll
    for (int g = 0; g < 16; ++g) vreg[g] = bf2f(sq[2048 + g * 64 + lane]);

    const int q_ = l >> 4, j = l & 15;
    const size_t base = ((size_t)b * 4096 + q_) * 1024 + j * 64 + lane;
#pragma unroll
    for (int h = 0; h < 16; ++h) {
        float acc = 0.f;
#pragma unroll
        for (int g = 0; g < 16; ++g) acc += Pl[wave][h * 16 + g] * vreg[g];
        scr[base + (size_t)h * 256 * 1024] = f2bf(acc);
    }
}

// ---------------- launch ----------------
extern "C" void kernel_launch(void* const* d_in, const int* in_sizes, int n_in,
                              void* d_out, int out_size, void* d_ws, size_t ws_size,
                              hipStream_t stream) {
    const float* x    = (const float*)d_in[0];   // [4,4096,1024]
    const float* Wqkv = (const float*)d_in[1];   // [3072,1024]
    const float* bqkv = (const float*)d_in[2];   // [3072]
    const float* Wout = (const float*)d_in[3];   // [1024,1024]
    const float* bout = (const float*)d_in[4];   // [1024]
    float* out = (float*)d_out;                  // [4,4096,1024] fp32

    char* ws = (char*)d_ws;
    unsigned short* xb   = (unsigned short*)(ws);
    unsigned short* wqb  = (unsigned short*)(ws + 33554432);
    unsigned short* wob  = (unsigned short*)(ws + 39845888);
    unsigned short* qkvb = (unsigned short*)(ws + 41943040);
    unsigned short* scr  = (unsigned short*)(ws + 142606336);

    cast_all<<<2560, 256, 0, stream>>>(x, Wqkv, Wout, xb, wqb, wob);

    // qkv = x @ Wqkv^T + bqkv  (M=16384, N=3072, K=1024), bf16 out; 768 blocks
    gemm256<0><<<768, 512, 0, stream>>>(xb, wqb, bqkv, qkvb, nullptr, 16384, 3072, 1024, 12);

    // per-token head attention -> scrambled layout
    attn_kernel<<<4096, 256, 0, stream>>>(qkvb, scr);

    // out = scr @ Wout^T + bout  (M=16384, N=1024, K=1024), fp32 out; 256 blocks
    gemm256<1><<<256, 512, 0, stream>>>(scr, wob, bout, nullptr, out, 16384, 1024, 1024, 4);
}